// Round 7
// baseline (1150.937 us; speedup 1.0000x reference)
//
#include <hip/hip_runtime.h>
#include <math.h>

// Gated delta-rule linear attention (Qwen3.5 GatedDeltaNet).
// Phase A: per-chunk preprocessing; emits operands pre-swizzled into MFMA
//   A-fragment layout as 2-way f16 splits (h+l, 3 MFMA products ~ fp32).
// Phase B: sequential scan, 1 wave per (bh, dv16), barrier-free software
//   pipeline: operands staged to LDS via global_load_lds a chunk ahead,
//   guarded by counted vmcnt waits; VC/gl prefetched into REGISTERS a chunk
//   ahead so the compiler never needs a vmcnt(0) drain mid-loop.

namespace {
constexpr int Bn = 2, Sn = 4096, Hn = 16, DKn = 128, DVn = 128, Cn = 64, Nn = 64;
// per-chunk ws bytes: KC h/l 2x16K @0, QG @32768, KD @65536, AT @98304 (2x8K),
// VC f32 @114688 (32K) => 144KB
constexpr long CHUNK_B = 147456;
constexpr long PER_BH_B = (long)Nn * CHUNK_B + Nn * 4;   // + GL floats
}

typedef __attribute__((ext_vector_type(4))) float f32x4;
typedef __attribute__((ext_vector_type(8))) _Float16 f16x8;
typedef __attribute__((ext_vector_type(4))) _Float16 f16x4;

__device__ __forceinline__ void fsplit(float x, _Float16& h, _Float16& l) {
  h = (_Float16)x;
  l = (_Float16)(x - (float)h);
}

__device__ __forceinline__ void gl_lds16(const void* g, void* l) {
  __builtin_amdgcn_global_load_lds(
      (const __attribute__((address_space(1))) void*)g,
      (__attribute__((address_space(3))) void*)l, 16, 0, 0);
}

__global__ __launch_bounds__(256, 1) void gdn_phaseA(
    const float* __restrict__ q, const float* __restrict__ k,
    const float* __restrict__ v, const float* __restrict__ g,
    const float* __restrict__ beta, char* __restrict__ wsb,
    int bh0, long ncp)
{
  __shared__ float sA[64][132];   // l2-normalized k  (later: VC stage)
  __shared__ float sQ[64][132];   // l2-normalized, scaled q (later: KC stage)
  __shared__ float sM[64][65];    // strict-lower M
  __shared__ float satt[64][68];  // attn (tril incl diag)
  __shared__ float s_gc[64], s_beta[64], s_egc[64], s_ekd[64];

  const int t  = threadIdx.x;
  const int pl = blockIdx.x;              // local chunk index within pass
  const int p  = bh0 * Nn + pl;
  const int n  = p % Nn;
  const int bh = p / Nn;
  const int h  = bh % Hn;
  const int b  = bh / Hn;
  const long base   = (((long)b * Sn + (long)n * Cn) * Hn + h) * DKn;
  const long rowstr = (long)Hn * DKn;                    // 2048
  const long gbase  = ((long)b * Sn + (long)n * Cn) * Hn + h;
  const long cb     = (long)pl * CHUNK_B;

  // ---- smalls ----
  if (t < 64) {
    s_beta[t] = beta[gbase + (long)t * Hn];
    sM[0][t]  = g[gbase + (long)t * Hn];
  }
  __syncthreads();
  if (t == 0) {
    float run = 0.f;
    #pragma unroll
    for (int c = 0; c < 64; ++c) { run += sM[0][c]; s_gc[c] = run; }
    ((float*)(wsb + ncp * CHUNK_B))[pl] = expf(run);     // GL
  }
  __syncthreads();
  if (t < 64) {
    s_egc[t] = expf(s_gc[t]);
    s_ekd[t] = expf(s_gc[63] - s_gc[t]);
  }

  // ---- load k, q ----
  #pragma unroll
  for (int i = 0; i < 8; ++i) {
    int idx = t + 256 * i;
    int c = idx >> 5;
    int d = (idx & 31) << 2;
    *(f32x4*)&sA[c][d] = *(const f32x4*)(k + base + (long)c * rowstr + d);
    *(f32x4*)&sQ[c][d] = *(const f32x4*)(q + base + (long)c * rowstr + d);
  }
  __syncthreads();

  // ---- l2norm (4 threads/row) ----
  {
    const int c = t >> 2, l4 = t & 3;
    float sk = 0.f, sq = 0.f;
    #pragma unroll
    for (int i = 0; i < 8; ++i) {
      f32x4 a  = *(const f32x4*)&sA[c][l4 * 32 + 4 * i];
      f32x4 qq = *(const f32x4*)&sQ[c][l4 * 32 + 4 * i];
      sk += a[0]*a[0] + a[1]*a[1] + a[2]*a[2] + a[3]*a[3];
      sq += qq[0]*qq[0] + qq[1]*qq[1] + qq[2]*qq[2] + qq[3]*qq[3];
    }
    sk += __shfl_xor(sk, 1, 64); sk += __shfl_xor(sk, 2, 64);
    sq += __shfl_xor(sq, 1, 64); sq += __shfl_xor(sq, 2, 64);
    const float rk = rsqrtf(sk + 1e-6f);
    const float rq = rsqrtf(sq + 1e-6f) * 0.08838834764831845f;
    #pragma unroll
    for (int i = 0; i < 8; ++i) {
      f32x4 a  = *(const f32x4*)&sA[c][l4 * 32 + 4 * i];
      f32x4 qq = *(const f32x4*)&sQ[c][l4 * 32 + 4 * i];
      a[0]*=rk; a[1]*=rk; a[2]*=rk; a[3]*=rk;
      qq[0]*=rq; qq[1]*=rq; qq[2]*=rq; qq[3]*=rq;
      *(f32x4*)&sA[c][l4 * 32 + 4 * i] = a;
      *(f32x4*)&sQ[c][l4 * 32 + 4 * i] = qq;
    }
  }
  __syncthreads();

  // ---- M (strict lower) and attn into LDS ----
  {
    const int d = t & 63;
    const int w = t >> 6;                  // 0..3
    float ma[16], qa[16];
    #pragma unroll
    for (int kk = 0; kk < 16; ++kk) { ma[kk] = 0.f; qa[kk] = 0.f; }
    for (int dd = 0; dd < 128; dd += 4) {
      f32x4 va = *(const f32x4*)&sA[d][dd];
      #pragma unroll
      for (int kk = 0; kk < 16; ++kk) {
        const int c = w + 4 * kk;
        f32x4 ka = *(const f32x4*)&sA[c][dd];
        f32x4 qv = *(const f32x4*)&sQ[c][dd];
        ma[kk] += ka[0]*va[0] + ka[1]*va[1] + ka[2]*va[2] + ka[3]*va[3];
        qa[kk] += qv[0]*va[0] + qv[1]*va[1] + qv[2]*va[2] + qv[3]*va[3];
      }
    }
    #pragma unroll
    for (int kk = 0; kk < 16; ++kk) {
      const int c = w + 4 * kk;
      const float dec = (c >= d) ? expf(s_gc[c] - s_gc[d]) : 0.f;
      satt[c][d] = qa[kk] * dec;
      sM[c][d] = (c > d) ? ma[kk] * s_beta[c] * dec : 0.f;
    }
  }
  __syncthreads();

  // ---- emissions in A-frag layout: o = tile*512 + lane*8 + idx (f16 h/l) ----
  // QG: A[64 c][128 dk], 16 tiles; val = sQ[row][k] * egc[row]
  {
    _Float16* Hh = (_Float16*)(wsb + cb + 32768);
    _Float16* Ll = (_Float16*)(wsb + cb + 49152);
    #pragma unroll
    for (int i = 0; i < 8; ++i) {
      int o = i * 1024 + t * 4;
      int tile = o >> 9, ln = (o >> 3) & 63;
      int row = (tile >> 2) * 16 + (ln & 15);
      int k0  = (tile & 3) * 32 + (ln >> 4) * 8 + (o & 7);
      float e = s_egc[row];
      f32x4 vv = *(const f32x4*)&sQ[row][k0];
      f16x4 hh, ll; _Float16 h_, l_;
      #pragma unroll
      for (int r = 0; r < 4; ++r) {
        fsplit(vv[r] * e, h_, l_);
        hh[r] = h_; ll[r] = l_;
      }
      *(f16x4*)(Hh + o) = hh; *(f16x4*)(Ll + o) = ll;
    }
  }
  // KDT: A[128 dk][64 c], 16 tiles; val = sA[k][row] * ekd[k]
  {
    _Float16* Hh = (_Float16*)(wsb + cb + 65536);
    _Float16* Ll = (_Float16*)(wsb + cb + 81920);
    #pragma unroll
    for (int i = 0; i < 8; ++i) {
      int o = i * 1024 + t * 4;
      int tile = o >> 9, ln = (o >> 3) & 63;
      int row = (tile >> 1) * 16 + (ln & 15);
      int k0  = (tile & 1) * 32 + (ln >> 4) * 8 + (o & 7);
      f16x4 hh, ll; _Float16 h_, l_;
      #pragma unroll
      for (int r = 0; r < 4; ++r) {
        fsplit(sA[k0 + r][row] * s_ekd[k0 + r], h_, l_);
        hh[r] = h_; ll[r] = l_;
      }
      *(f16x4*)(Hh + o) = hh; *(f16x4*)(Ll + o) = ll;
    }
  }
  // ATT: A[64 c][64 c], 8 tiles; val = satt[row][k]
  {
    _Float16* Hh = (_Float16*)(wsb + cb + 98304);
    _Float16* Ll = (_Float16*)(wsb + cb + 106496);
    #pragma unroll
    for (int i = 0; i < 4; ++i) {
      int o = i * 1024 + t * 4;
      int tile = o >> 9, ln = (o >> 3) & 63;
      int row = (tile >> 1) * 16 + (ln & 15);
      int k0  = (tile & 1) * 32 + (ln >> 4) * 8 + (o & 7);
      f16x4 hh, ll; _Float16 h_, l_;
      #pragma unroll
      for (int r = 0; r < 4; ++r) {
        fsplit(satt[row][k0 + r], h_, l_);
        hh[r] = h_; ll[r] = l_;
      }
      *(f16x4*)(Hh + o) = hh; *(f16x4*)(Ll + o) = ll;
    }
  }

  // ---- forward substitution (I+M) X = RHS, column-per-thread ----
  float X[64];
  {
    const int j = t;
    if (j < 128) {
      #pragma unroll
      for (int i = 0; i < 64; ++i) X[i] = sA[i][j] * s_beta[i] * s_egc[i];
    } else {
      const int jj = j - 128;
      #pragma unroll
      for (int i = 0; i < 64; ++i)
        X[i] = v[base + (long)i * rowstr + jj] * s_beta[i];
    }
    #pragma unroll
    for (int i = 1; i < 64; ++i) {
      float s0 = 0.f, s1 = 0.f;
      #pragma unroll
      for (int l = 0; l < i - 1; l += 2) {
        s0 += sM[i][l]     * X[l];
        s1 += sM[i][l + 1] * X[l + 1];
      }
      if ((i & 1) != 0) s0 += sM[i][i - 1] * X[i - 1];
      X[i] = X[i] - s0 - s1;
    }
  }
  __syncthreads();   // all sA/sQ readers (emissions + X init) done

  // stage: KC columns into sQ, VC columns into sA
  if (t < 128) {
    #pragma unroll
    for (int c = 0; c < 64; ++c) sQ[c][t] = X[c];
  } else {
    #pragma unroll
    for (int c = 0; c < 64; ++c) sA[c][t - 128] = X[c];
  }
  __syncthreads();

  // KC: A[64 c][128 dk], 16 tiles from sQ
  {
    _Float16* Hh = (_Float16*)(wsb + cb);
    _Float16* Ll = (_Float16*)(wsb + cb + 16384);
    #pragma unroll
    for (int i = 0; i < 8; ++i) {
      int o = i * 1024 + t * 4;
      int tile = o >> 9, ln = (o >> 3) & 63;
      int row = (tile >> 2) * 16 + (ln & 15);
      int k0  = (tile & 3) * 32 + (ln >> 4) * 8 + (o & 7);
      f32x4 vv = *(const f32x4*)&sQ[row][k0];
      f16x4 hh, ll; _Float16 h_, l_;
      #pragma unroll
      for (int r = 0; r < 4; ++r) {
        fsplit(vv[r], h_, l_);
        hh[r] = h_; ll[r] = l_;
      }
      *(f16x4*)(Hh + o) = hh; *(f16x4*)(Ll + o) = ll;
    }
  }
  // VC: C-frag layout f32 [jb 8][ct 4][lane 64][r 4] from sA
  {
    float* VC = (float*)(wsb + cb + 114688);
    #pragma unroll
    for (int i = 0; i < 8; ++i) {
      int o = i * 1024 + t * 4;
      int jbv = o >> 10, ct = (o >> 8) & 3, ln = (o >> 2) & 63;
      int c0 = ct * 16 + (ln >> 4) * 4;
      int jj = jbv * 16 + (ln & 15);
      f32x4 vv;
      vv[0] = sA[c0 + 0][jj]; vv[1] = sA[c0 + 1][jj];
      vv[2] = sA[c0 + 2][jj]; vv[3] = sA[c0 + 3][jj];
      *(f32x4*)(VC + o) = vv;
    }
  }
}

#define MFMA16(D, A, B) D = __builtin_amdgcn_mfma_f32_16x16x32_f16(A, B, D, 0, 0, 0)

// counted vmcnt guard: every guarded group has >=100 younger VMEM issues,
// so vmcnt(48) guarantees the group retired (in-order retirement, m135).
#define VMW(N) do { asm volatile("s_waitcnt vmcnt(" #N ")" ::: "memory"); \
                    __builtin_amdgcn_sched_barrier(0); } while (0)
#define LGW() do { asm volatile("s_waitcnt lgkmcnt(0)" ::: "memory"); \
                   __builtin_amdgcn_sched_barrier(0); } while (0)

#define STAGE(dst, srcB, nt) do {                                     \
    const char* s_ = (const char*)(srcB);                             \
    char* d_ = (char*)(dst);                                          \
    _Pragma("unroll")                                                 \
    for (int t_ = 0; t_ < (nt); ++t_)                                 \
      gl_lds16(s_ + t_ * 1024 + lane * 16, d_ + t_ * 1024 + lane * 16); \
  } while (0)

__global__ __launch_bounds__(64, 1) void gdn_phaseB(
    const char* __restrict__ wsb, float* __restrict__ out,
    int bh0, long ncp, int grp)
{
  __shared__ __align__(16) _Float16 sKC[2][2][8192];  // 64KB [buf][h/l]
  __shared__ __align__(16) _Float16 sQG[2][8192];     // 32KB [h/l]
  __shared__ __align__(16) _Float16 sKD[2][8192];     // 32KB
  __shared__ __align__(16) _Float16 sAT[2][4096];     // 16KB
  __shared__ __align__(16) _Float16 Sb[2][16][136];   // state B-frag bounce
  __shared__ __align__(16) _Float16 Ub[2][16][72];    // u B-frag bounce

  const int lane = threadIdx.x;
  const int jrow = lane & 15;
  const int kgrp = lane >> 4;
  const int blk  = blockIdx.x;
  const int bhl  = blk % grp;       // 8 jb-sharers of a bh land on one XCD
  const int jb   = blk / grp;
  const int bh   = bh0 + bhl;
  const int h    = bh % Hn;
  const int b    = bh / Hn;
  const float* GLp = (const float*)(wsb + ncp * CHUNK_B);

  f32x4 S[8];
  const f32x4 zero = {0.f, 0.f, 0.f, 0.f};
  #pragma unroll
  for (int i = 0; i < 8; ++i) S[i] = zero;
  for (int i = lane; i < 2 * 16 * 136; i += 64) (&Sb[0][0][0])[i] = (_Float16)0.f;

  const char* cbase = wsb + (long)bhl * Nn * CHUNK_B;

  // register prefetch of chunk 0's VC slice + gl (issued BEFORE the stages so
  // their compiler-inserted wait is a counted, satisfied one)
  f32x4 vcv[4];
  {
    const float* VCp = (const float*)(cbase + 114688);
    #pragma unroll
    for (int ct = 0; ct < 4; ++ct)
      vcv[ct] = *(const f32x4*)(VCp + ((jb * 4 + ct) * 64 + lane) * 4);
  }
  float gl = GLp[(long)bhl * Nn];

  // prologue: stage chunk 0 (KC->buf0, QG, AT, KD)
  STAGE(sKC[0][0], cbase +      0, 16); STAGE(sKC[0][1], cbase +  16384, 16);
  STAGE(sQG[0],    cbase +  32768, 16); STAGE(sQG[1],    cbase +  49152, 16);
  STAGE(sAT[0],    cbase +  98304,  8); STAGE(sAT[1],    cbase + 106496,  8);
  STAGE(sKD[0],    cbase +  65536, 16); STAGE(sKD[1],    cbase +  81920, 16);

  float* outb = out + ((long)b * Sn) * (long)(Hn * DVn) + (long)h * DVn + jb * 16 + jrow;

  int cur = 0;
  #pragma unroll 1
  for (int n = 0; n < Nn; ++n) {
    const int  np  = (n + 1 < Nn) ? n + 1 : n;
    const char* cbn = cbase + (long)np * CHUNK_B;

    // register prefetch of NEXT chunk's VC slice + gl
    f32x4 vcvN[4];
    {
      const float* VCn = (const float*)(cbn + 114688);
      #pragma unroll
      for (int ct = 0; ct < 4; ++ct)
        vcvN[ct] = *(const f32x4*)(VCn + ((jb * 4 + ct) * 64 + lane) * 4);
    }
    const float glN = GLp[(long)bhl * Nn + np];

    // stage KC(n+1) into other buffer (double-buffered)
    STAGE(sKC[cur ^ 1][0], cbn +     0, 16);
    STAGE(sKC[cur ^ 1][1], cbn + 16384, 16);

    VMW(48);  // KC(n) resident (>=132 younger issues)

    // state B-frags (zeros for n==0)
    f16x8 sbh[4], sbl[4];
    #pragma unroll
    for (int kt = 0; kt < 4; ++kt) {
      sbh[kt] = *(const f16x8*)&Sb[0][jrow][kt * 32 + kgrp * 8];
      sbl[kt] = *(const f16x8*)&Sb[1][jrow][kt * 32 + kgrp * 8];
    }

    // m1: acc = kc @ S  (3 independent MFMA streams, depth 4)
    f32x4 aA[4], aB[4], aC[4];
    #pragma unroll
    for (int i = 0; i < 4; ++i) { aA[i] = zero; aB[i] = zero; aC[i] = zero; }
    #pragma unroll
    for (int kt = 0; kt < 4; ++kt) {
      #pragma unroll
      for (int mt = 0; mt < 4; ++mt) {
        const int tl = mt * 4 + kt;
        f16x8 ah = *(const f16x8*)&sKC[cur][0][tl * 512 + lane * 8];
        f16x8 al = *(const f16x8*)&sKC[cur][1][tl * 512 + lane * 8];
        MFMA16(aA[mt], ah, sbh[kt]);
        MFMA16(aB[mt], ah, sbl[kt]);
        MFMA16(aC[mt], al, sbh[kt]);
      }
    }
    // u = v_c - acc -> Ub
    #pragma unroll
    for (int ct = 0; ct < 4; ++ct) {
      f32x4 uu = vcv[ct] - (aA[ct] + aB[ct] + aC[ct]);
      f16x4 hh, ll; _Float16 h_, l_;
      #pragma unroll
      for (int r = 0; r < 4; ++r) { fsplit(uu[r], h_, l_); hh[r] = h_; ll[r] = l_; }
      *(f16x4*)&Ub[0][jrow][ct * 16 + kgrp * 4] = hh;
      *(f16x4*)&Ub[1][jrow][ct * 16 + kgrp * 4] = ll;
    }

    VMW(48);  // QG(n) resident (>=100 younger issues)
    // m2a: o = qg @ S  (3 streams)
    f32x4 oA[4], oB[4], oC[4];
    #pragma unroll
    for (int i = 0; i < 4; ++i) { oA[i] = zero; oB[i] = zero; oC[i] = zero; }
    #pragma unroll
    for (int kt = 0; kt < 4; ++kt) {
      #pragma unroll
      for (int mt = 0; mt < 4; ++mt) {
        const int tl = mt * 4 + kt;
        f16x8 ah = *(const f16x8*)&sQG[0][tl * 512 + lane * 8];
        f16x8 al = *(const f16x8*)&sQG[1][tl * 512 + lane * 8];
        MFMA16(oA[mt], ah, sbh[kt]);
        MFMA16(oB[mt], ah, sbl[kt]);
        MFMA16(oC[mt], al, sbh[kt]);
      }
    }
    LGW();  // QG(n) ds_reads retired -> safe to overwrite
    STAGE(sQG[0], cbn + 32768, 16); STAGE(sQG[1], cbn + 49152, 16);

    VMW(48);  // AT(n) resident (>=116 younger issues)
    // u B-frags
    f16x8 ubh[2], ubl[2];
    #pragma unroll
    for (int kt2 = 0; kt2 < 2; ++kt2) {
      ubh[kt2] = *(const f16x8*)&Ub[0][jrow][kt2 * 32 + kgrp * 8];
      ubl[kt2] = *(const f16x8*)&Ub[1][jrow][kt2 * 32 + kgrp * 8];
    }
    // m2b: o += att @ u (append to same 3 streams, depth 6 total)
    #pragma unroll
    for (int kt2 = 0; kt2 < 2; ++kt2) {
      #pragma unroll
      for (int mt = 0; mt < 4; ++mt) {
        const int tl = mt * 2 + kt2;
        f16x8 ah = *(const f16x8*)&sAT[0][tl * 512 + lane * 8];
        f16x8 al = *(const f16x8*)&sAT[1][tl * 512 + lane * 8];
        MFMA16(oA[mt], ah, ubh[kt2]);
        MFMA16(oB[mt], ah, ubl[kt2]);
        MFMA16(oC[mt], al, ubh[kt2]);
      }
    }
    LGW();
    STAGE(sAT[0], cbn + 98304, 8); STAGE(sAT[1], cbn + 106496, 8);

    // out stores
    {
      float* orow = outb + (long)(n * 64) * (Hn * DVn);
      #pragma unroll
      for (int ct = 0; ct < 4; ++ct) {
        f32x4 o4 = oA[ct] + oB[ct] + oC[ct];
        #pragma unroll
        for (int r = 0; r < 4; ++r)
          orow[(long)(ct * 16 + kgrp * 4 + r) * (Hn * DVn)] = o4[r];
      }
    }

    // m3: S = gl*S + kdT @ u
    #pragma unroll
    for (int i = 0; i < 8; ++i) {
      S[i][0] *= gl; S[i][1] *= gl; S[i][2] *= gl; S[i][3] *= gl;
    }
    VMW(48);  // KD(n) resident (>=100 younger issues)
    #pragma unroll
    for (int kt2 = 0; kt2 < 2; ++kt2) {
      #pragma unroll
      for (int dt = 0; dt < 8; ++dt) {
        const int tl = dt * 2 + kt2;
        f16x8 ah = *(const f16x8*)&sKD[0][tl * 512 + lane * 8];
        f16x8 al = *(const f16x8*)&sKD[1][tl * 512 + lane * 8];
        MFMA16(S[dt], ah, ubh[kt2]);
        MFMA16(S[dt], ah, ubl[kt2]);
        MFMA16(S[dt], al, ubh[kt2]);
      }
    }
    LGW();
    STAGE(sKD[0], cbn + 65536, 16); STAGE(sKD[1], cbn + 81920, 16);

    // redistribute S -> Sb for next chunk
    #pragma unroll
    for (int dt = 0; dt < 8; ++dt) {
      f16x4 hh, ll; _Float16 h_, l_;
      #pragma unroll
      for (int r = 0; r < 4; ++r) { fsplit(S[dt][r], h_, l_); hh[r] = h_; ll[r] = l_; }
      *(f16x4*)&Sb[0][jrow][dt * 16 + kgrp * 4] = hh;
      *(f16x4*)&Sb[1][jrow][dt * 16 + kgrp * 4] = ll;
    }

    // rotate register prefetches
    #pragma unroll
    for (int ct = 0; ct < 4; ++ct) vcv[ct] = vcvN[ct];
    gl = glN;
    cur ^= 1;
  }
}

extern "C" void kernel_launch(void* const* d_in, const int* in_sizes, int n_in,
                              void* d_out, int out_size, void* d_ws, size_t ws_size,
                              hipStream_t stream) {
  (void)in_sizes; (void)n_in; (void)out_size;
  const float* q    = (const float*)d_in[0];
  const float* k    = (const float*)d_in[1];
  const float* v    = (const float*)d_in[2];
  const float* g    = (const float*)d_in[3];
  const float* beta = (const float*)d_in[4];
  char*  ws  = (char*)d_ws;
  float* out = (float*)d_out;

  const int NBH = Bn * Hn;                                // 32
  long fit = (long)(ws_size / (size_t)PER_BH_B);
  int G = (int)(fit < 1 ? 1 : (fit > NBH ? NBH : fit));   // bh per pass
  const long ncp = (long)G * Nn;                          // chunk capacity/pass

  for (int bh0 = 0; bh0 < NBH; bh0 += G) {
    const int grp = (bh0 + G <= NBH) ? G : (NBH - bh0);
    hipLaunchKernelGGL(gdn_phaseA, dim3(grp * Nn), dim3(256), 0, stream,
                       q, k, v, g, beta, ws, bh0, ncp);
    hipLaunchKernelGGL(gdn_phaseB, dim3(grp * 8), dim3(64), 0, stream,
                       ws, out, bh0, ncp, grp);
  }
}

// Round 8
// 915.223 us; speedup vs baseline: 1.2575x; 1.2575x over previous
//
#include <hip/hip_runtime.h>
#include <math.h>

// Gated delta-rule linear attention (Qwen3.5 GatedDeltaNet).
// Phase A: per-chunk preprocessing; emits operands pre-swizzled into MFMA
//   A-fragment layout as 2-way f16 splits (h+l, 3 MFMA products ~ fp32).
// Phase B: sequential scan. 2 blocks per bh, 4 waves per block (one per dv16
//   slice); staged operands shared in LDS (each wave stages 1/4), phases
//   separated by raw s_barrier + counted per-wave vmcnt (T3/T4 idiom).
//   Single-buffered staging: each buffer re-staged right after the barrier
//   that certifies all waves finished reading it.

namespace {
constexpr int Bn = 2, Sn = 4096, Hn = 16, DKn = 128, DVn = 128, Cn = 64, Nn = 64;
// per-chunk ws bytes: KC h/l @0/16384, QG @32768/49152, KD @65536/81920,
// AT(6 nonzero tiles) h @98304 l @104448, VC f32 @110592 (32K) => 140KB
constexpr long CHUNK_B = 143360;
constexpr long PER_BH_B = (long)Nn * CHUNK_B + Nn * 4;   // + GL floats
}

typedef __attribute__((ext_vector_type(4))) float f32x4;
typedef __attribute__((ext_vector_type(8))) _Float16 f16x8;
typedef __attribute__((ext_vector_type(4))) _Float16 f16x4;

__device__ __forceinline__ void fsplit(float x, _Float16& h, _Float16& l) {
  h = (_Float16)x;
  l = (_Float16)(x - (float)h);
}

__device__ __forceinline__ void gl_lds16(const void* g, void* l) {
  __builtin_amdgcn_global_load_lds(
      (const __attribute__((address_space(1))) void*)g,
      (__attribute__((address_space(3))) void*)l, 16, 0, 0);
}

__global__ __launch_bounds__(256, 1) void gdn_phaseA(
    const float* __restrict__ q, const float* __restrict__ k,
    const float* __restrict__ v, const float* __restrict__ g,
    const float* __restrict__ beta, char* __restrict__ wsb,
    int bh0, long ncp)
{
  __shared__ float sA[64][132];   // l2-normalized k  (later: VC stage)
  __shared__ float sQ[64][132];   // l2-normalized, scaled q (later: KC stage)
  __shared__ float sM[64][65];    // strict-lower M
  __shared__ float satt[64][68];  // attn (tril incl diag)
  __shared__ float s_gc[64], s_beta[64], s_egc[64], s_ekd[64];

  const int t  = threadIdx.x;
  const int pl = blockIdx.x;              // local chunk index within pass
  const int p  = bh0 * Nn + pl;
  const int n  = p % Nn;
  const int bh = p / Nn;
  const int h  = bh % Hn;
  const int b  = bh / Hn;
  const long base   = (((long)b * Sn + (long)n * Cn) * Hn + h) * DKn;
  const long rowstr = (long)Hn * DKn;                    // 2048
  const long gbase  = ((long)b * Sn + (long)n * Cn) * Hn + h;
  const long cb     = (long)pl * CHUNK_B;

  // ---- smalls ----
  if (t < 64) {
    s_beta[t] = beta[gbase + (long)t * Hn];
    sM[0][t]  = g[gbase + (long)t * Hn];
  }
  __syncthreads();
  if (t == 0) {
    float run = 0.f;
    #pragma unroll
    for (int c = 0; c < 64; ++c) { run += sM[0][c]; s_gc[c] = run; }
    ((float*)(wsb + ncp * CHUNK_B))[pl] = expf(run);     // GL
  }
  __syncthreads();
  if (t < 64) {
    s_egc[t] = expf(s_gc[t]);
    s_ekd[t] = expf(s_gc[63] - s_gc[t]);
  }

  // ---- load k, q ----
  #pragma unroll
  for (int i = 0; i < 8; ++i) {
    int idx = t + 256 * i;
    int c = idx >> 5;
    int d = (idx & 31) << 2;
    *(f32x4*)&sA[c][d] = *(const f32x4*)(k + base + (long)c * rowstr + d);
    *(f32x4*)&sQ[c][d] = *(const f32x4*)(q + base + (long)c * rowstr + d);
  }
  __syncthreads();

  // ---- l2norm (4 threads/row) ----
  {
    const int c = t >> 2, l4 = t & 3;
    float sk = 0.f, sq = 0.f;
    #pragma unroll
    for (int i = 0; i < 8; ++i) {
      f32x4 a  = *(const f32x4*)&sA[c][l4 * 32 + 4 * i];
      f32x4 qq = *(const f32x4*)&sQ[c][l4 * 32 + 4 * i];
      sk += a[0]*a[0] + a[1]*a[1] + a[2]*a[2] + a[3]*a[3];
      sq += qq[0]*qq[0] + qq[1]*qq[1] + qq[2]*qq[2] + qq[3]*qq[3];
    }
    sk += __shfl_xor(sk, 1, 64); sk += __shfl_xor(sk, 2, 64);
    sq += __shfl_xor(sq, 1, 64); sq += __shfl_xor(sq, 2, 64);
    const float rk = rsqrtf(sk + 1e-6f);
    const float rq = rsqrtf(sq + 1e-6f) * 0.08838834764831845f;
    #pragma unroll
    for (int i = 0; i < 8; ++i) {
      f32x4 a  = *(const f32x4*)&sA[c][l4 * 32 + 4 * i];
      f32x4 qq = *(const f32x4*)&sQ[c][l4 * 32 + 4 * i];
      a[0]*=rk; a[1]*=rk; a[2]*=rk; a[3]*=rk;
      qq[0]*=rq; qq[1]*=rq; qq[2]*=rq; qq[3]*=rq;
      *(f32x4*)&sA[c][l4 * 32 + 4 * i] = a;
      *(f32x4*)&sQ[c][l4 * 32 + 4 * i] = qq;
    }
  }
  __syncthreads();

  // ---- M (strict lower) and attn into LDS ----
  {
    const int d = t & 63;
    const int w = t >> 6;                  // 0..3
    float ma[16], qa[16];
    #pragma unroll
    for (int kk = 0; kk < 16; ++kk) { ma[kk] = 0.f; qa[kk] = 0.f; }
    for (int dd = 0; dd < 128; dd += 4) {
      f32x4 va = *(const f32x4*)&sA[d][dd];
      #pragma unroll
      for (int kk = 0; kk < 16; ++kk) {
        const int c = w + 4 * kk;
        f32x4 ka = *(const f32x4*)&sA[c][dd];
        f32x4 qv = *(const f32x4*)&sQ[c][dd];
        ma[kk] += ka[0]*va[0] + ka[1]*va[1] + ka[2]*va[2] + ka[3]*va[3];
        qa[kk] += qv[0]*va[0] + qv[1]*va[1] + qv[2]*va[2] + qv[3]*va[3];
      }
    }
    #pragma unroll
    for (int kk = 0; kk < 16; ++kk) {
      const int c = w + 4 * kk;
      const float dec = (c >= d) ? expf(s_gc[c] - s_gc[d]) : 0.f;
      satt[c][d] = qa[kk] * dec;
      sM[c][d] = (c > d) ? ma[kk] * s_beta[c] * dec : 0.f;
    }
  }
  __syncthreads();

  // ---- emissions in A-frag layout: o = tile*512 + lane*8 + idx (f16 h/l) ----
  // QG: A[64 c][128 dk], 16 tiles; val = sQ[row][k] * egc[row]
  {
    _Float16* Hh = (_Float16*)(wsb + cb + 32768);
    _Float16* Ll = (_Float16*)(wsb + cb + 49152);
    #pragma unroll
    for (int i = 0; i < 8; ++i) {
      int o = i * 1024 + t * 4;
      int tile = o >> 9, ln = (o >> 3) & 63;
      int row = (tile >> 2) * 16 + (ln & 15);
      int k0  = (tile & 3) * 32 + (ln >> 4) * 8 + (o & 7);
      float e = s_egc[row];
      f32x4 vv = *(const f32x4*)&sQ[row][k0];
      f16x4 hh, ll; _Float16 h_, l_;
      #pragma unroll
      for (int r = 0; r < 4; ++r) {
        fsplit(vv[r] * e, h_, l_);
        hh[r] = h_; ll[r] = l_;
      }
      *(f16x4*)(Hh + o) = hh; *(f16x4*)(Ll + o) = ll;
    }
  }
  // KDT: A[128 dk][64 c], 16 tiles; val = sA[k][row] * ekd[k]
  {
    _Float16* Hh = (_Float16*)(wsb + cb + 65536);
    _Float16* Ll = (_Float16*)(wsb + cb + 81920);
    #pragma unroll
    for (int i = 0; i < 8; ++i) {
      int o = i * 1024 + t * 4;
      int tile = o >> 9, ln = (o >> 3) & 63;
      int row = (tile >> 1) * 16 + (ln & 15);
      int k0  = (tile & 1) * 32 + (ln >> 4) * 8 + (o & 7);
      f16x4 hh, ll; _Float16 h_, l_;
      #pragma unroll
      for (int r = 0; r < 4; ++r) {
        fsplit(sA[k0 + r][row] * s_ekd[k0 + r], h_, l_);
        hh[r] = h_; ll[r] = l_;
      }
      *(f16x4*)(Hh + o) = hh; *(f16x4*)(Ll + o) = ll;
    }
  }
  // ATT: 6 nonzero tiles (causal): slot s -> (mt, kt2): s<4:(s,0); 4:(2,1); 5:(3,1)
  {
    _Float16* Hh = (_Float16*)(wsb + cb + 98304);
    _Float16* Ll = (_Float16*)(wsb + cb + 104448);
    #pragma unroll
    for (int i = 0; i < 3; ++i) {
      int o = i * 1024 + t * 4;            // f16 index in 6-slot space
      int s = o >> 9, ln = (o >> 3) & 63;
      int mt  = (s < 4) ? s : (s - 2);
      int kt2 = (s < 4) ? 0 : 1;
      int row = mt * 16 + (ln & 15);
      int k0  = kt2 * 32 + (ln >> 4) * 8 + (o & 7);
      f16x4 hh, ll; _Float16 h_, l_;
      #pragma unroll
      for (int r = 0; r < 4; ++r) {
        fsplit(satt[row][k0 + r], h_, l_);
        hh[r] = h_; ll[r] = l_;
      }
      *(f16x4*)(Hh + o) = hh; *(f16x4*)(Ll + o) = ll;
    }
  }

  // ---- forward substitution (I+M) X = RHS, column-per-thread ----
  float X[64];
  {
    const int j = t;
    if (j < 128) {
      #pragma unroll
      for (int i = 0; i < 64; ++i) X[i] = sA[i][j] * s_beta[i] * s_egc[i];
    } else {
      const int jj = j - 128;
      #pragma unroll
      for (int i = 0; i < 64; ++i)
        X[i] = v[base + (long)i * rowstr + jj] * s_beta[i];
    }
    #pragma unroll
    for (int i = 1; i < 64; ++i) {
      float s0 = 0.f, s1 = 0.f;
      #pragma unroll
      for (int l = 0; l < i - 1; l += 2) {
        s0 += sM[i][l]     * X[l];
        s1 += sM[i][l + 1] * X[l + 1];
      }
      if ((i & 1) != 0) s0 += sM[i][i - 1] * X[i - 1];
      X[i] = X[i] - s0 - s1;
    }
  }
  __syncthreads();   // all sA/sQ readers (emissions + X init) done

  // stage: KC columns into sQ, VC columns into sA
  if (t < 128) {
    #pragma unroll
    for (int c = 0; c < 64; ++c) sQ[c][t] = X[c];
  } else {
    #pragma unroll
    for (int c = 0; c < 64; ++c) sA[c][t - 128] = X[c];
  }
  __syncthreads();

  // KC: A[64 c][128 dk], 16 tiles from sQ
  {
    _Float16* Hh = (_Float16*)(wsb + cb);
    _Float16* Ll = (_Float16*)(wsb + cb + 16384);
    #pragma unroll
    for (int i = 0; i < 8; ++i) {
      int o = i * 1024 + t * 4;
      int tile = o >> 9, ln = (o >> 3) & 63;
      int row = (tile >> 2) * 16 + (ln & 15);
      int k0  = (tile & 3) * 32 + (ln >> 4) * 8 + (o & 7);
      f32x4 vv = *(const f32x4*)&sQ[row][k0];
      f16x4 hh, ll; _Float16 h_, l_;
      #pragma unroll
      for (int r = 0; r < 4; ++r) {
        fsplit(vv[r], h_, l_);
        hh[r] = h_; ll[r] = l_;
      }
      *(f16x4*)(Hh + o) = hh; *(f16x4*)(Ll + o) = ll;
    }
  }
  // VC: C-frag layout f32 [jb 8][ct 4][lane 64][r 4] from sA
  {
    float* VC = (float*)(wsb + cb + 110592);
    #pragma unroll
    for (int i = 0; i < 8; ++i) {
      int o = i * 1024 + t * 4;
      int jbv = o >> 10, ct = (o >> 8) & 3, ln = (o >> 2) & 63;
      int c0 = ct * 16 + (ln >> 4) * 4;
      int jj = jbv * 16 + (ln & 15);
      f32x4 vv;
      vv[0] = sA[c0 + 0][jj]; vv[1] = sA[c0 + 1][jj];
      vv[2] = sA[c0 + 2][jj]; vv[3] = sA[c0 + 3][jj];
      *(f32x4*)(VC + o) = vv;
    }
  }
}

#define MFMA16(D, A, B) D = __builtin_amdgcn_mfma_f32_16x16x32_f16(A, B, D, 0, 0, 0)

#define VMW(N) do { asm volatile("s_waitcnt vmcnt(" #N ")" ::: "memory"); \
                    __builtin_amdgcn_sched_barrier(0); } while (0)
#define BAR() do { __builtin_amdgcn_s_barrier(); \
                   __builtin_amdgcn_sched_barrier(0); } while (0)

// per-wave 1/4 share of an nt-KB staging region
#define STAGEW(dst, srcB, nt) do {                                    \
    const char* s_ = (const char*)(srcB);                             \
    char* d_ = (char*)(dst);                                          \
    _Pragma("unroll")                                                 \
    for (int t_ = wave; t_ < (nt); t_ += 4)                           \
      gl_lds16(s_ + t_ * 1024 + lane * 16, d_ + t_ * 1024 + lane * 16); \
  } while (0)

__global__ __launch_bounds__(256, 1) void gdn_phaseB(
    const char* __restrict__ wsb, float* __restrict__ out,
    int bh0, long ncp, int grp)
{
  __shared__ __align__(16) _Float16 sKCh[8192], sKCl[8192];   // 32KB
  __shared__ __align__(16) _Float16 sQGh[8192], sQGl[8192];   // 32KB
  __shared__ __align__(16) _Float16 sKDh[8192], sKDl[8192];   // 32KB
  __shared__ __align__(16) _Float16 sAT[6144];                // 12KB (h|l)
  __shared__ __align__(16) _Float16 Sb[4][2][16][128];        // 32KB
  __shared__ __align__(16) _Float16 Ub[4][2][16][64];         // 16KB

  const int tid  = threadIdx.x;
  const int wave = tid >> 6;
  const int lane = tid & 63;
  const int jrow = lane & 15;
  const int kgrp = lane >> 4;
  const int jx3  = (jrow & 7) << 3;     // XOR swizzle for Sb/Ub cols

  const int blk = blockIdx.x;
  int bhl, half;
  if ((grp & 7) == 0) {                  // XCD-stable: sharers on one XCD
    const int e = grp >> 3;
    bhl  = (blk & 7) * e + ((blk >> 3) % e);
    half = (blk >> 3) / e;
  } else { bhl = blk % grp; half = blk / grp; }
  const int jb = half * 4 + wave;
  const int bh = bh0 + bhl;
  const int h  = bh % Hn;
  const int b  = bh / Hn;
  const float* GLp = (const float*)(wsb + ncp * CHUNK_B);
  const char* cbase = wsb + (long)bhl * Nn * CHUNK_B;

  f32x4 S[8];
  const f32x4 zero = {0.f, 0.f, 0.f, 0.f};
  #pragma unroll
  for (int i = 0; i < 8; ++i) S[i] = zero;
  for (int i = lane; i < 2 * 16 * 128; i += 64)
    (&Sb[wave][0][0][0])[i] = (_Float16)0.f;

  // prologue: VC(0) regs + stage chunk 0 (KC, QG, AT); KD(0) staged at P0e
  f32x4 vcv[4];
  {
    const float* VC0 = (const float*)(cbase + 110592);
    #pragma unroll
    for (int ct = 0; ct < 4; ++ct)
      vcv[ct] = *(const f32x4*)(VC0 + ((jb * 4 + ct) * 64 + lane) * 4);
  }
  STAGEW(sKCh, cbase +     0, 16); STAGEW(sKCl, cbase + 16384, 16);
  STAGEW(sQGh, cbase + 32768, 16); STAGEW(sQGl, cbase + 49152, 16);
  STAGEW(sAT,  cbase + 98304, 12);
  asm volatile("s_waitcnt vmcnt(0) lgkmcnt(0)" ::: "memory");
  __builtin_amdgcn_sched_barrier(0);
  BAR();

  float* outb = out + ((long)b * Sn) * (long)(Hn * DVn) + (long)h * DVn + jb * 16 + jrow;

  #pragma unroll 1
  for (int n = 0; n < Nn; ++n) {
    const int  np  = (n + 1 < Nn) ? n + 1 : n;
    const char* cbp = cbase + (long)n  * CHUNK_B;
    const char* cbn = cbase + (long)np * CHUNK_B;

    // ---- P0e: KC(n)+VC(n) resident ----
    VMW(27); BAR();
    STAGEW(sKDh, cbp + 65536, 16); STAGEW(sKDl, cbp + 81920, 16);  // KD(n)
    f32x4 vcvN[4];
    {
      const float* VCn = (const float*)(cbn + 110592);
      #pragma unroll
      for (int ct = 0; ct < 4; ++ct)
        vcvN[ct] = *(const f32x4*)(VCn + ((jb * 4 + ct) * 64 + lane) * 4);
    }

    // P0: state B-frags + m1
    f16x8 sbh[4], sbl[4];
    #pragma unroll
    for (int kt = 0; kt < 4; ++kt) {
      const int cx = (kt * 32 + kgrp * 8) ^ jx3;
      sbh[kt] = *(const f16x8*)&Sb[wave][0][jrow][cx];
      sbl[kt] = *(const f16x8*)&Sb[wave][1][jrow][cx];
    }
    f32x4 aA[4], aB[4], aC[4];
    #pragma unroll
    for (int i = 0; i < 4; ++i) { aA[i] = zero; aB[i] = zero; aC[i] = zero; }
    #pragma unroll
    for (int kt = 0; kt < 4; ++kt) {
      #pragma unroll
      for (int mt = 0; mt < 4; ++mt) {
        const int tl = mt * 4 + kt;
        f16x8 ah = *(const f16x8*)&sKCh[tl * 512 + lane * 8];
        f16x8 al = *(const f16x8*)&sKCl[tl * 512 + lane * 8];
        MFMA16(aA[mt], ah, sbh[kt]);
        MFMA16(aB[mt], ah, sbl[kt]);
        MFMA16(aC[mt], al, sbh[kt]);
      }
    }
    #pragma unroll
    for (int ct = 0; ct < 4; ++ct) {
      f32x4 uu = vcv[ct] - (aA[ct] + aB[ct] + aC[ct]);
      f16x4 hh, ll; _Float16 h_, l_;
      #pragma unroll
      for (int r = 0; r < 4; ++r) { fsplit(uu[r], h_, l_); hh[r] = h_; ll[r] = l_; }
      const int cu = (ct * 16 + kgrp * 4) ^ jx3;
      *(f16x4*)&Ub[wave][0][jrow][cu] = hh;
      *(f16x4*)&Ub[wave][1][jrow][cu] = ll;
    }

    // ---- P1e: QG(n) resident; all P0 reads certified -> restage KC(n+1) ----
    VMW(31); BAR();
    STAGEW(sKCh, cbn +     0, 16); STAGEW(sKCl, cbn + 16384, 16);

    // P1: m2a
    f32x4 oA[4], oB[4], oC[4];
    #pragma unroll
    for (int i = 0; i < 4; ++i) { oA[i] = zero; oB[i] = zero; oC[i] = zero; }
    #pragma unroll
    for (int kt = 0; kt < 4; ++kt) {
      #pragma unroll
      for (int mt = 0; mt < 4; ++mt) {
        const int tl = mt * 4 + kt;
        f16x8 ah = *(const f16x8*)&sQGh[tl * 512 + lane * 8];
        f16x8 al = *(const f16x8*)&sQGl[tl * 512 + lane * 8];
        MFMA16(oA[mt], ah, sbh[kt]);
        MFMA16(oB[mt], ah, sbl[kt]);
        MFMA16(oC[mt], al, sbh[kt]);
      }
    }

    // ---- P2e: AT(n) resident; P1 reads certified -> restage QG(n+1) ----
    VMW(20); BAR();
    STAGEW(sQGh, cbn + 32768, 16); STAGEW(sQGl, cbn + 49152, 16);

    // P2: u B-frags, m2b (skip zero tiles), stores
    f16x8 ubh[2], ubl[2];
    #pragma unroll
    for (int kt2 = 0; kt2 < 2; ++kt2) {
      const int cx = (kt2 * 32 + kgrp * 8) ^ jx3;
      ubh[kt2] = *(const f16x8*)&Ub[wave][0][jrow][cx];
      ubl[kt2] = *(const f16x8*)&Ub[wave][1][jrow][cx];
    }
    #pragma unroll
    for (int kt2 = 0; kt2 < 2; ++kt2) {
      #pragma unroll
      for (int mt = 0; mt < 4; ++mt) {
        if (kt2 == 1 && mt < 2) continue;          // zero tiles (causal)
        const int slot = (kt2 == 0) ? mt : (mt + 2);
        f16x8 ah = *(const f16x8*)&sAT[slot * 512 + lane * 8];
        f16x8 al = *(const f16x8*)&sAT[3072 + slot * 512 + lane * 8];
        MFMA16(oA[mt], ah, ubh[kt2]);
        MFMA16(oB[mt], ah, ubl[kt2]);
        MFMA16(oC[mt], al, ubh[kt2]);
      }
    }
    {
      float* orow = outb + (long)(n * 64) * (Hn * DVn);
      #pragma unroll
      for (int ct = 0; ct < 4; ++ct) {
        f32x4 o4 = oA[ct] + oB[ct] + oC[ct];
        #pragma unroll
        for (int r = 0; r < 4; ++r)
          orow[(long)(ct * 16 + kgrp * 4 + r) * (Hn * DVn)] = o4[r];
      }
    }

    // ---- P3e: KD(n) resident; P2 reads certified -> restage AT(n+1) ----
    VMW(32); BAR();
    STAGEW(sAT, cbn + 98304, 12);

    // P3: m3
    const float gl = GLp[(long)bhl * Nn + n];
    #pragma unroll
    for (int i = 0; i < 8; ++i) {
      S[i][0] *= gl; S[i][1] *= gl; S[i][2] *= gl; S[i][3] *= gl;
    }
    #pragma unroll
    for (int kt2 = 0; kt2 < 2; ++kt2) {
      #pragma unroll
      for (int dt = 0; dt < 8; ++dt) {
        const int tl = dt * 2 + kt2;
        f16x8 ah = *(const f16x8*)&sKDh[tl * 512 + lane * 8];
        f16x8 al = *(const f16x8*)&sKDl[tl * 512 + lane * 8];
        MFMA16(S[dt], ah, ubh[kt2]);
        MFMA16(S[dt], ah, ubl[kt2]);
        MFMA16(S[dt], al, ubh[kt2]);
      }
    }
    // redistribute S -> Sb for next chunk
    #pragma unroll
    for (int dt = 0; dt < 8; ++dt) {
      f16x4 hh, ll; _Float16 h_, l_;
      #pragma unroll
      for (int r = 0; r < 4; ++r) { fsplit(S[dt][r], h_, l_); hh[r] = h_; ll[r] = l_; }
      const int cx = (dt * 16 + kgrp * 4) ^ jx3;
      *(f16x4*)&Sb[wave][0][jrow][cx] = hh;
      *(f16x4*)&Sb[wave][1][jrow][cx] = ll;
    }

    #pragma unroll
    for (int ct = 0; ct < 4; ++ct) vcv[ct] = vcvN[ct];
  }
}

extern "C" void kernel_launch(void* const* d_in, const int* in_sizes, int n_in,
                              void* d_out, int out_size, void* d_ws, size_t ws_size,
                              hipStream_t stream) {
  (void)in_sizes; (void)n_in; (void)out_size;
  const float* q    = (const float*)d_in[0];
  const float* k    = (const float*)d_in[1];
  const float* v    = (const float*)d_in[2];
  const float* g    = (const float*)d_in[3];
  const float* beta = (const float*)d_in[4];
  char*  ws  = (char*)d_ws;
  float* out = (float*)d_out;

  const int NBH = Bn * Hn;                                // 32
  long fit = (long)(ws_size / (size_t)PER_BH_B);
  int G = fit >= 32 ? 32 : fit >= 24 ? 24 : fit >= 16 ? 16 : fit >= 8 ? 8
        : (int)(fit < 1 ? 1 : fit);                       // multiple of 8 if possible
  const long ncp = (long)G * Nn;                          // chunk capacity/pass

  for (int bh0 = 0; bh0 < NBH; bh0 += G) {
    const int grp = (bh0 + G <= NBH) ? G : (NBH - bh0);
    hipLaunchKernelGGL(gdn_phaseA, dim3(grp * Nn), dim3(256), 0, stream,
                       q, k, v, g, beta, ws, bh0, ncp);
    hipLaunchKernelGGL(gdn_phaseB, dim3(grp * 2), dim3(256), 0, stream,
                       ws, out, bh0, ncp, grp);
  }
}

// Round 9
// 768.536 us; speedup vs baseline: 1.4976x; 1.1909x over previous
//
#include <hip/hip_runtime.h>
#include <math.h>

// Gated delta-rule linear attention (Qwen3.5 GatedDeltaNet).
// Phase A (512 thr): MFMA-based M/attn (f16 h/l 3-product), exp-table decay,
//   wave-split epilogue: waves 0-3 solve + direct KC/VC reg->global emission,
//   waves 4-7 emit QG/KDT/ATT. f16 operands in XOR-swizzled LDS.
// Phase B: unchanged from round 8 (4-wave shared-LDS pipelined scan).

namespace {
constexpr int Bn = 2, Sn = 4096, Hn = 16, DKn = 128, DVn = 128, Cn = 64, Nn = 64;
// per-chunk ws bytes: KC h/l @0/16384, QG @32768/49152, KD @65536/81920,
// AT(6 nonzero tiles) h @98304 l @104448, VC f32 @110592 (32K) => 140KB
constexpr long CHUNK_B = 143360;
constexpr long PER_BH_B = (long)Nn * CHUNK_B + Nn * 4;   // + GL floats
}

typedef __attribute__((ext_vector_type(4))) float f32x4;
typedef __attribute__((ext_vector_type(8))) _Float16 f16x8;
typedef __attribute__((ext_vector_type(4))) _Float16 f16x4;

__device__ __forceinline__ void fsplit(float x, _Float16& h, _Float16& l) {
  h = (_Float16)x;
  l = (_Float16)(x - (float)h);
}

__device__ __forceinline__ void gl_lds16(const void* g, void* l) {
  __builtin_amdgcn_global_load_lds(
      (const __attribute__((address_space(1))) void*)g,
      (__attribute__((address_space(3))) void*)l, 16, 0, 0);
}

#define MFMA16(D, A, B) D = __builtin_amdgcn_mfma_f32_16x16x32_f16(A, B, D, 0, 0, 0)

// f16 LDS [64][128], 8-elem granules XOR-swizzled by row&7
__device__ __forceinline__ int sidx(int r, int dk) {
  return r * 128 + (((dk >> 3) ^ (r & 7)) << 3) + (dk & 7);
}

__global__ __launch_bounds__(512, 1) void gdn_phaseA(
    const float* __restrict__ q, const float* __restrict__ k,
    const float* __restrict__ v, const float* __restrict__ g,
    const float* __restrict__ beta, char* __restrict__ wsb,
    int bh0, long ncp)
{
  __shared__ __align__(16) _Float16 sAh[8192], sAl[8192];   // k norm h/l
  __shared__ __align__(16) _Float16 sQh[8192], sQl[8192];   // q norm*scale h/l
  __shared__ float sM[64][66];                              // strict-lower M
  __shared__ __align__(16) float satt[4096];                // attn, swizzled
  __shared__ __align__(16) float sV[64 * 132];              // v chunk
  __shared__ float s_gc[64], s_egc[64], s_inv[64], s_ekd[64], s_beta[64];

  const int t    = threadIdx.x;
  const int lane = t & 63;
  const int w    = t >> 6;
  const int pl = blockIdx.x;
  const int p  = bh0 * Nn + pl;
  const int n  = p % Nn;
  const int bhx = p / Nn;
  const int hh_ = bhx % Hn;
  const int bb_ = bhx / Hn;
  const long base   = (((long)bb_ * Sn + (long)n * Cn) * Hn + hh_) * DKn;
  const long rowstr = (long)Hn * DKn;                    // 2048
  const long gbase  = ((long)bb_ * Sn + (long)n * Cn) * Hn + hh_;
  const long cb     = (long)pl * CHUNK_B;

  // ---- stage v chunk into sV (coalesced) ----
  #pragma unroll
  for (int i = 0; i < 4; ++i) {
    int idx = t + 512 * i;
    int r = idx >> 5, c4 = (idx & 31) << 2;
    *(f32x4*)&sV[r * 132 + c4] = *(const f32x4*)(v + base + (long)r * rowstr + c4);
  }

  // ---- smalls + wave-parallel scan (wave 0) ----
  if (t < 64) {
    s_beta[t] = beta[gbase + (long)t * Hn];
    float x = g[gbase + (long)t * Hn];
    #pragma unroll
    for (int s = 1; s < 64; s <<= 1) {
      float y = __shfl_up(x, s, 64);
      if (t >= s) x += y;
    }
    s_gc[t]  = x;
    float eg = expf(x);
    s_egc[t] = eg;
    s_inv[t] = expf(-x);
    float g63 = __shfl(x, 63, 64);
    s_ekd[t] = expf(g63 - x);
    if (t == 63) ((float*)(wsb + ncp * CHUNK_B))[pl] = eg;   // GL = exp(gc[63])
  }

  // ---- q/k load + l2norm (8 thr/row) + f16 split to swizzled LDS ----
  {
    const int r = t >> 3, sub = t & 7;
    f32x4 ka[4], qa[4];
    #pragma unroll
    for (int i = 0; i < 4; ++i) {
      ka[i] = *(const f32x4*)(k + base + (long)r * rowstr + sub * 16 + 4 * i);
      qa[i] = *(const f32x4*)(q + base + (long)r * rowstr + sub * 16 + 4 * i);
    }
    float sk = 0.f, sq = 0.f;
    #pragma unroll
    for (int i = 0; i < 4; ++i) {
      sk += ka[i][0]*ka[i][0] + ka[i][1]*ka[i][1] + ka[i][2]*ka[i][2] + ka[i][3]*ka[i][3];
      sq += qa[i][0]*qa[i][0] + qa[i][1]*qa[i][1] + qa[i][2]*qa[i][2] + qa[i][3]*qa[i][3];
    }
    sk += __shfl_xor(sk, 1, 64); sk += __shfl_xor(sk, 2, 64); sk += __shfl_xor(sk, 4, 64);
    sq += __shfl_xor(sq, 1, 64); sq += __shfl_xor(sq, 2, 64); sq += __shfl_xor(sq, 4, 64);
    const float rk = rsqrtf(sk + 1e-6f);
    const float rq = rsqrtf(sq + 1e-6f) * 0.08838834764831845f;  // * Dk^-0.5
    #pragma unroll
    for (int i = 0; i < 4; ++i) {
      const int dk0 = sub * 16 + 4 * i;
      const int go = sidx(r, dk0);
      f16x4 h4, l4, qh4, ql4;
      #pragma unroll
      for (int e = 0; e < 4; ++e) {
        _Float16 h_, l_;
        fsplit(ka[i][e] * rk, h_, l_); h4[e] = h_; l4[e] = l_;
        fsplit(qa[i][e] * rq, h_, l_); qh4[e] = h_; ql4[e] = l_;
      }
      *(f16x4*)&sAh[go] = h4;  *(f16x4*)&sAl[go] = l4;
      *(f16x4*)&sQh[go] = qh4; *(f16x4*)&sQl[go] = ql4;
    }
  }
  __syncthreads();

  // ---- MFMA: kkT (symmetric operand) and attT = k·qT; epilogues ----
  {
    const int mt  = w & 3;          // row-tile (r for kkT, d for att)
    const int tc0 = (w >> 2) * 2;   // col-tile base (2 tiles per wave)
    const f32x4 zero = {0.f, 0.f, 0.f, 0.f};
    f32x4 mk0 = zero, mk1 = zero, ma0 = zero, ma1 = zero;
    #pragma unroll
    for (int kt = 0; kt < 4; ++kt) {
      const int rA = mt * 16 + (lane & 15);
      const int gA = rA * 128 + (((kt * 4 + (lane >> 4)) ^ (rA & 7)) << 3);
      f16x8 fa_h = *(const f16x8*)&sAh[gA];
      f16x8 fa_l = *(const f16x8*)&sAl[gA];
      #pragma unroll
      for (int j = 0; j < 2; ++j) {
        const int rB = (tc0 + j) * 16 + (lane & 15);
        const int gB = rB * 128 + (((kt * 4 + (lane >> 4)) ^ (rB & 7)) << 3);
        f16x8 fb_h = *(const f16x8*)&sAh[gB];
        f16x8 fb_l = *(const f16x8*)&sAl[gB];
        f16x8 fq_h = *(const f16x8*)&sQh[gB];
        f16x8 fq_l = *(const f16x8*)&sQl[gB];
        if (j == 0) {
          MFMA16(mk0, fa_h, fb_h); MFMA16(mk0, fa_h, fb_l); MFMA16(mk0, fa_l, fb_h);
          MFMA16(ma0, fa_h, fq_h); MFMA16(ma0, fa_h, fq_l); MFMA16(ma0, fa_l, fq_h);
        } else {
          MFMA16(mk1, fa_h, fb_h); MFMA16(mk1, fa_h, fb_l); MFMA16(mk1, fa_l, fb_h);
          MFMA16(ma1, fa_h, fq_h); MFMA16(ma1, fa_h, fq_l); MFMA16(ma1, fa_l, fq_h);
        }
      }
    }
    // epilogues: sM (strict lower, beta*decay) and satt (tril, decay)
    const int r0 = mt * 16 + (lane >> 4) * 4;
    #pragma unroll
    for (int j = 0; j < 2; ++j) {
      const int scol = (tc0 + j) * 16 + (lane & 15);
      const f32x4 mkv = (j == 0) ? mk0 : mk1;
      const f32x4 mav = (j == 0) ? ma0 : ma1;
      #pragma unroll
      for (int e = 0; e < 4; ++e) {
        const int r = r0 + e;
        sM[r][scol] = (r > scol) ? mkv[e] * s_beta[r] * s_egc[r] * s_inv[scol] : 0.f;
      }
      f32x4 av;
      #pragma unroll
      for (int e = 0; e < 4; ++e) {
        const int d = r0 + e;
        av[e] = (scol >= d) ? mav[e] * s_egc[scol] * s_inv[d] : 0.f;
      }
      satt[scol * 64 + (((r0 >> 2) ^ (scol & 3)) << 2)] = av[0];
      *(f32x4*)&satt[scol * 64 + (((r0 >> 2) ^ (scol & 3)) << 2)] = av;
    }
  }
  __syncthreads();

  if (t < 256) {
    // ---- waves 0-3: forward substitution + direct KC/VC emission ----
    float X[64];
    const int j = t;
    if (j < 128) {
      #pragma unroll
      for (int i = 0; i < 64; ++i) {
        const int go = sidx(i, j);
        X[i] = ((float)sAh[go] + (float)sAl[go]) * s_beta[i] * s_egc[i];
      }
    } else {
      const int jj = j - 128;
      #pragma unroll
      for (int i = 0; i < 64; ++i)
        X[i] = sV[i * 132 + jj] * s_beta[i];
    }
    #pragma unroll
    for (int i = 1; i < 64; ++i) {
      float s0 = 0.f, s1 = 0.f;
      #pragma unroll
      for (int l = 0; l < i - 1; l += 2) {
        s0 += sM[i][l]     * X[l];
        s1 += sM[i][l + 1] * X[l + 1];
      }
      if ((i & 1) != 0) s0 += sM[i][i - 1] * X[i - 1];
      X[i] = X[i] - s0 - s1;
    }
    if (j < 128) {
      _Float16* KCh = (_Float16*)(wsb + cb);
      _Float16* KCl = (_Float16*)(wsb + cb + 16384);
      #pragma unroll
      for (int c = 0; c < 64; ++c) {
        const int tile = (c >> 4) * 4 + (j >> 5);
        const int ln_  = ((j >> 3) & 3) * 16 + (c & 15);
        const int o = tile * 512 + ln_ * 8 + (j & 7);
        _Float16 h_, l_; fsplit(X[c], h_, l_);
        KCh[o] = h_; KCl[o] = l_;
      }
    } else {
      float* VC = (float*)(wsb + cb + 110592);
      const int jj = j - 128;
      #pragma unroll
      for (int a = 0; a < 16; ++a) {
        f32x4 xx;
        xx[0] = X[4*a]; xx[1] = X[4*a+1]; xx[2] = X[4*a+2]; xx[3] = X[4*a+3];
        const int eo = ((jj >> 4) * 4 + (a >> 2)) * 256 + ((a & 3) * 16 + (jj & 15)) * 4;
        *(f32x4*)&VC[eo] = xx;
      }
    }
  } else {
    // ---- waves 4-7: QG / KDT / ATT emissions ----
    const int tt = t - 256;
    // QG: A[64 c][128 dk]; val = q_norm*scale*egc[row]
    {
      _Float16* Hh = (_Float16*)(wsb + cb + 32768);
      _Float16* Ll = (_Float16*)(wsb + cb + 49152);
      #pragma unroll
      for (int i = 0; i < 8; ++i) {
        int o = i * 1024 + tt * 4;
        int tile = o >> 9, ln = (o >> 3) & 63;
        int row = (tile >> 2) * 16 + (ln & 15);
        int k0  = (tile & 3) * 32 + (ln >> 4) * 8 + (o & 7);
        const int go = sidx(row, k0);
        f16x4 qh4 = *(const f16x4*)&sQh[go];
        f16x4 ql4 = *(const f16x4*)&sQl[go];
        const float eg = s_egc[row];
        f16x4 hh, ll;
        #pragma unroll
        for (int r = 0; r < 4; ++r) {
          _Float16 h_, l_;
          fsplit(((float)qh4[r] + (float)ql4[r]) * eg, h_, l_);
          hh[r] = h_; ll[r] = l_;
        }
        *(f16x4*)(Hh + o) = hh; *(f16x4*)(Ll + o) = ll;
      }
    }
    // KDT: A[128 dk][64 c]; val = k_norm[c][dk] * ekd[c]
    {
      _Float16* Hh = (_Float16*)(wsb + cb + 65536);
      _Float16* Ll = (_Float16*)(wsb + cb + 81920);
      #pragma unroll
      for (int i = 0; i < 8; ++i) {
        int o = i * 1024 + tt * 4;
        int tile = o >> 9, ln = (o >> 3) & 63;
        int row = (tile >> 1) * 16 + (ln & 15);     // dk
        int k0  = (tile & 1) * 32 + (ln >> 4) * 8 + (o & 7);  // c
        f16x4 hh, ll;
        #pragma unroll
        for (int r = 0; r < 4; ++r) {
          const int c = k0 + r;
          const int go = sidx(c, row);
          _Float16 h_, l_;
          fsplit(((float)sAh[go] + (float)sAl[go]) * s_ekd[c], h_, l_);
          hh[r] = h_; ll[r] = l_;
        }
        *(f16x4*)(Hh + o) = hh; *(f16x4*)(Ll + o) = ll;
      }
    }
    // ATT: 6 nonzero tiles; slot s -> (mt,kt2): s<4:(s,0); 4:(2,1); 5:(3,1)
    {
      _Float16* Hh = (_Float16*)(wsb + cb + 98304);
      _Float16* Ll = (_Float16*)(wsb + cb + 104448);
      #pragma unroll
      for (int i = 0; i < 3; ++i) {
        int o = i * 1024 + tt * 4;
        int s = o >> 9, ln = (o >> 3) & 63;
        int mt  = (s < 4) ? s : (s - 2);
        int kt2 = (s < 4) ? 0 : 1;
        int row = mt * 16 + (ln & 15);
        int k0  = kt2 * 32 + (ln >> 4) * 8 + (o & 7);
        f32x4 av = *(const f32x4*)&satt[row * 64 + ((((k0 >> 2) ^ (row & 3))) << 2)];
        f16x4 hh, ll;
        #pragma unroll
        for (int r = 0; r < 4; ++r) {
          _Float16 h_, l_; fsplit(av[r], h_, l_);
          hh[r] = h_; ll[r] = l_;
        }
        *(f16x4*)(Hh + o) = hh; *(f16x4*)(Ll + o) = ll;
      }
    }
  }
}

#define VMW(N) do { asm volatile("s_waitcnt vmcnt(" #N ")" ::: "memory"); \
                    __builtin_amdgcn_sched_barrier(0); } while (0)
#define BAR() do { __builtin_amdgcn_s_barrier(); \
                   __builtin_amdgcn_sched_barrier(0); } while (0)

// per-wave 1/4 share of an nt-KB staging region
#define STAGEW(dst, srcB, nt) do {                                    \
    const char* s_ = (const char*)(srcB);                             \
    char* d_ = (char*)(dst);                                          \
    _Pragma("unroll")                                                 \
    for (int t_ = wave; t_ < (nt); t_ += 4)                           \
      gl_lds16(s_ + t_ * 1024 + lane * 16, d_ + t_ * 1024 + lane * 16); \
  } while (0)

__global__ __launch_bounds__(256, 1) void gdn_phaseB(
    const char* __restrict__ wsb, float* __restrict__ out,
    int bh0, long ncp, int grp)
{
  __shared__ __align__(16) _Float16 sKCh[8192], sKCl[8192];   // 32KB
  __shared__ __align__(16) _Float16 sQGh[8192], sQGl[8192];   // 32KB
  __shared__ __align__(16) _Float16 sKDh[8192], sKDl[8192];   // 32KB
  __shared__ __align__(16) _Float16 sAT[6144];                // 12KB (h|l)
  __shared__ __align__(16) _Float16 Sb[4][2][16][128];        // 32KB
  __shared__ __align__(16) _Float16 Ub[4][2][16][64];         // 16KB

  const int tid  = threadIdx.x;
  const int wave = tid >> 6;
  const int lane = tid & 63;
  const int jrow = lane & 15;
  const int kgrp = lane >> 4;
  const int jx3  = (jrow & 7) << 3;     // XOR swizzle for Sb/Ub cols

  const int blk = blockIdx.x;
  int bhl, half;
  if ((grp & 7) == 0) {                  // XCD-stable: sharers on one XCD
    const int e = grp >> 3;
    bhl  = (blk & 7) * e + ((blk >> 3) % e);
    half = (blk >> 3) / e;
  } else { bhl = blk % grp; half = blk / grp; }
  const int jb = half * 4 + wave;
  const int bh = bh0 + bhl;
  const int h  = bh % Hn;
  const int b  = bh / Hn;
  const float* GLp = (const float*)(wsb + ncp * CHUNK_B);
  const char* cbase = wsb + (long)bhl * Nn * CHUNK_B;

  f32x4 S[8];
  const f32x4 zero = {0.f, 0.f, 0.f, 0.f};
  #pragma unroll
  for (int i = 0; i < 8; ++i) S[i] = zero;
  for (int i = lane; i < 2 * 16 * 128; i += 64)
    (&Sb[wave][0][0][0])[i] = (_Float16)0.f;

  // prologue: VC(0) regs + stage chunk 0 (KC, QG, AT); KD(0) staged at P0e
  f32x4 vcv[4];
  {
    const float* VC0 = (const float*)(cbase + 110592);
    #pragma unroll
    for (int ct = 0; ct < 4; ++ct)
      vcv[ct] = *(const f32x4*)(VC0 + ((jb * 4 + ct) * 64 + lane) * 4);
  }
  STAGEW(sKCh, cbase +     0, 16); STAGEW(sKCl, cbase + 16384, 16);
  STAGEW(sQGh, cbase + 32768, 16); STAGEW(sQGl, cbase + 49152, 16);
  STAGEW(sAT,  cbase + 98304, 12);
  asm volatile("s_waitcnt vmcnt(0) lgkmcnt(0)" ::: "memory");
  __builtin_amdgcn_sched_barrier(0);
  BAR();

  float* outb = out + ((long)b * Sn) * (long)(Hn * DVn) + (long)h * DVn + jb * 16 + jrow;

  #pragma unroll 1
  for (int n = 0; n < Nn; ++n) {
    const int  np  = (n + 1 < Nn) ? n + 1 : n;
    const char* cbp = cbase + (long)n  * CHUNK_B;
    const char* cbn = cbase + (long)np * CHUNK_B;

    // ---- P0e: KC(n)+VC(n) resident ----
    VMW(27); BAR();
    STAGEW(sKDh, cbp + 65536, 16); STAGEW(sKDl, cbp + 81920, 16);  // KD(n)
    f32x4 vcvN[4];
    {
      const float* VCn = (const float*)(cbn + 110592);
      #pragma unroll
      for (int ct = 0; ct < 4; ++ct)
        vcvN[ct] = *(const f32x4*)(VCn + ((jb * 4 + ct) * 64 + lane) * 4);
    }

    // P0: state B-frags + m1
    f16x8 sbh[4], sbl[4];
    #pragma unroll
    for (int kt = 0; kt < 4; ++kt) {
      const int cx = (kt * 32 + kgrp * 8) ^ jx3;
      sbh[kt] = *(const f16x8*)&Sb[wave][0][jrow][cx];
      sbl[kt] = *(const f16x8*)&Sb[wave][1][jrow][cx];
    }
    f32x4 aA[4], aB[4], aC[4];
    #pragma unroll
    for (int i = 0; i < 4; ++i) { aA[i] = zero; aB[i] = zero; aC[i] = zero; }
    #pragma unroll
    for (int kt = 0; kt < 4; ++kt) {
      #pragma unroll
      for (int mt = 0; mt < 4; ++mt) {
        const int tl = mt * 4 + kt;
        f16x8 ah = *(const f16x8*)&sKCh[tl * 512 + lane * 8];
        f16x8 al = *(const f16x8*)&sKCl[tl * 512 + lane * 8];
        MFMA16(aA[mt], ah, sbh[kt]);
        MFMA16(aB[mt], ah, sbl[kt]);
        MFMA16(aC[mt], al, sbh[kt]);
      }
    }
    #pragma unroll
    for (int ct = 0; ct < 4; ++ct) {
      f32x4 uu = vcv[ct] - (aA[ct] + aB[ct] + aC[ct]);
      f16x4 hh, ll; _Float16 h_, l_;
      #pragma unroll
      for (int r = 0; r < 4; ++r) { fsplit(uu[r], h_, l_); hh[r] = h_; ll[r] = l_; }
      const int cu = (ct * 16 + kgrp * 4) ^ jx3;
      *(f16x4*)&Ub[wave][0][jrow][cu] = hh;
      *(f16x4*)&Ub[wave][1][jrow][cu] = ll;
    }

    // ---- P1e: QG(n) resident; all P0 reads certified -> restage KC(n+1) ----
    VMW(31); BAR();
    STAGEW(sKCh, cbn +     0, 16); STAGEW(sKCl, cbn + 16384, 16);

    // P1: m2a
    f32x4 oA[4], oB[4], oC[4];
    #pragma unroll
    for (int i = 0; i < 4; ++i) { oA[i] = zero; oB[i] = zero; oC[i] = zero; }
    #pragma unroll
    for (int kt = 0; kt < 4; ++kt) {
      #pragma unroll
      for (int mt = 0; mt < 4; ++mt) {
        const int tl = mt * 4 + kt;
        f16x8 ah = *(const f16x8*)&sQGh[tl * 512 + lane * 8];
        f16x8 al = *(const f16x8*)&sQGl[tl * 512 + lane * 8];
        MFMA16(oA[mt], ah, sbh[kt]);
        MFMA16(oB[mt], ah, sbl[kt]);
        MFMA16(oC[mt], al, sbh[kt]);
      }
    }

    // ---- P2e: AT(n) resident; P1 reads certified -> restage QG(n+1) ----
    VMW(20); BAR();
    STAGEW(sQGh, cbn + 32768, 16); STAGEW(sQGl, cbn + 49152, 16);

    // P2: u B-frags, m2b (skip zero tiles), stores
    f16x8 ubh[2], ubl[2];
    #pragma unroll
    for (int kt2 = 0; kt2 < 2; ++kt2) {
      const int cx = (kt2 * 32 + kgrp * 8) ^ jx3;
      ubh[kt2] = *(const f16x8*)&Ub[wave][0][jrow][cx];
      ubl[kt2] = *(const f16x8*)&Ub[wave][1][jrow][cx];
    }
    #pragma unroll
    for (int kt2 = 0; kt2 < 2; ++kt2) {
      #pragma unroll
      for (int mt = 0; mt < 4; ++mt) {
        if (kt2 == 1 && mt < 2) continue;          // zero tiles (causal)
        const int slot = (kt2 == 0) ? mt : (mt + 2);
        f16x8 ah = *(const f16x8*)&sAT[slot * 512 + lane * 8];
        f16x8 al = *(const f16x8*)&sAT[3072 + slot * 512 + lane * 8];
        MFMA16(oA[mt], ah, ubh[kt2]);
        MFMA16(oB[mt], ah, ubl[kt2]);
        MFMA16(oC[mt], al, ubh[kt2]);
      }
    }
    {
      float* orow = outb + (long)(n * 64) * (Hn * DVn);
      #pragma unroll
      for (int ct = 0; ct < 4; ++ct) {
        f32x4 o4 = oA[ct] + oB[ct] + oC[ct];
        #pragma unroll
        for (int r = 0; r < 4; ++r)
          orow[(long)(ct * 16 + kgrp * 4 + r) * (Hn * DVn)] = o4[r];
      }
    }

    // ---- P3e: KD(n) resident; P2 reads certified -> restage AT(n+1) ----
    VMW(32); BAR();
    STAGEW(sAT, cbn + 98304, 12);

    // P3: m3
    const float gl = GLp[(long)bhl * Nn + n];
    #pragma unroll
    for (int i = 0; i < 8; ++i) {
      S[i][0] *= gl; S[i][1] *= gl; S[i][2] *= gl; S[i][3] *= gl;
    }
    #pragma unroll
    for (int kt2 = 0; kt2 < 2; ++kt2) {
      #pragma unroll
      for (int dt = 0; dt < 8; ++dt) {
        const int tl = dt * 2 + kt2;
        f16x8 ah = *(const f16x8*)&sKDh[tl * 512 + lane * 8];
        f16x8 al = *(const f16x8*)&sKDl[tl * 512 + lane * 8];
        MFMA16(S[dt], ah, ubh[kt2]);
        MFMA16(S[dt], ah, ubl[kt2]);
        MFMA16(S[dt], al, ubh[kt2]);
      }
    }
    // redistribute S -> Sb for next chunk
    #pragma unroll
    for (int dt = 0; dt < 8; ++dt) {
      f16x4 hh, ll; _Float16 h_, l_;
      #pragma unroll
      for (int r = 0; r < 4; ++r) { fsplit(S[dt][r], h_, l_); hh[r] = h_; ll[r] = l_; }
      const int cx = (dt * 16 + kgrp * 4) ^ jx3;
      *(f16x4*)&Sb[wave][0][jrow][cx] = hh;
      *(f16x4*)&Sb[wave][1][jrow][cx] = ll;
    }

    #pragma unroll
    for (int ct = 0; ct < 4; ++ct) vcv[ct] = vcvN[ct];
  }
}

extern "C" void kernel_launch(void* const* d_in, const int* in_sizes, int n_in,
                              void* d_out, int out_size, void* d_ws, size_t ws_size,
                              hipStream_t stream) {
  (void)in_sizes; (void)n_in; (void)out_size;
  const float* q    = (const float*)d_in[0];
  const float* k    = (const float*)d_in[1];
  const float* v    = (const float*)d_in[2];
  const float* g    = (const float*)d_in[3];
  const float* beta = (const float*)d_in[4];
  char*  ws  = (char*)d_ws;
  float* out = (float*)d_out;

  const int NBH = Bn * Hn;                                // 32
  long fit = (long)(ws_size / (size_t)PER_BH_B);
  int G = fit >= 32 ? 32 : fit >= 24 ? 24 : fit >= 16 ? 16 : fit >= 8 ? 8
        : (int)(fit < 1 ? 1 : fit);                       // multiple of 8 if possible
  const long ncp = (long)G * Nn;                          // chunk capacity/pass

  for (int bh0 = 0; bh0 < NBH; bh0 += G) {
    const int grp = (bh0 + G <= NBH) ? G : (NBH - bh0);
    hipLaunchKernelGGL(gdn_phaseA, dim3(grp * Nn), dim3(512), 0, stream,
                       q, k, v, g, beta, ws, bh0, ncp);
    hipLaunchKernelGGL(gdn_phaseB, dim3(grp * 2), dim3(256), 0, stream,
                       ws, out, bh0, ncp, grp);
  }
}